// Round 1
// baseline (273.580 us; speedup 1.0000x reference)
//
#include <hip/hip_runtime.h>
#include <math.h>

// Problem constants (from reference):
// B=128, R=4608, K=2, O=32, I=16
#define NB 128
#define NR 4608
#define NK 2
#define NO 32
#define NI 16
#define NKO 64          // K*O
#define NBKO (NB*NKO)   // 8192
#define NRK (NR*NK)     // 9216

// ws layout (floats):
//   u_hat [B][R][KO]   : U_OFF,  37,748,736 floats (151 MB)
//   s     [B][KO]      : S_OFF,  8192
//   v     [B][KO]      : V_OFF,  8192
//   bij   [R][K]       : BIJ_OFF, 9216
//   c     [R][K]       : C_OFF,  9216

static const size_t U_OFF   = 0;
static const size_t U_SZ    = (size_t)NB * NR * NKO;
static const size_t S_OFF   = U_OFF + U_SZ;
static const size_t V_OFF   = S_OFF + NBKO;
static const size_t BIJ_OFF = V_OFF + NBKO;
static const size_t C_OFF   = BIJ_OFF + NRK;

// ---------------------------------------------------------------------------
// zero bij (ws is poisoned 0xAA before every timed launch)
__global__ void k_zero_bij(float* __restrict__ bij) {
    int i = blockIdx.x * blockDim.x + threadIdx.x;
    if (i < NRK) bij[i] = 0.0f;
}

// ---------------------------------------------------------------------------
// u_hat[b,r,ko] = sum_i W[r,ko,i] * x[b,r,i]
// one block per r; W row (1024 f) + x rows (128x16 f) staged in LDS.
__global__ __launch_bounds__(256) void k_uhat(const float* __restrict__ x,
                                              const float* __restrict__ W,
                                              float* __restrict__ u) {
    __shared__ float Wl[64 * 17];    // +1-pad on I=16 stride (bank-conflict fix)
    __shared__ float xl[128 * 16];

    const int r = blockIdx.x;
    const int t = threadIdx.x;

    // stage W[r] : 1024 floats, coalesced
    const float* Wr = W + (size_t)r * 1024;
    for (int e = t; e < 1024; e += 256) {
        int ko = e >> 4, i = e & 15;
        Wl[ko * 17 + i] = Wr[e];
    }
    // stage x[:, r, :] : 128 rows of 64B, float4 per thread
    for (int f = t; f < 512; f += 256) {
        int b = f >> 2, q = f & 3;
        float4 vv = *(const float4*)(x + ((size_t)b * NR + r) * NI + q * 4);
        *(float4*)&xl[b * 16 + q * 4] = vv;
    }
    __syncthreads();

    const int ko = t & 63;
    const int w  = t >> 6;

    // W fragment for this thread's ko -> registers (read once)
    float W0[16];
#pragma unroll
    for (int i = 0; i < 16; ++i) W0[i] = Wl[ko * 17 + i];

    // each wave handles 32 contiguous b's; x reads are wave-broadcast
    for (int j = 0; j < 32; ++j) {
        int b = w * 32 + j;
        const float4* xb = (const float4*)&xl[b * 16];
        float4 xa = xb[0], xc = xb[1], xe = xb[2], xg = xb[3];
        float acc;
        acc  = W0[0]  * xa.x + W0[1]  * xa.y + W0[2]  * xa.z + W0[3]  * xa.w;
        acc += W0[4]  * xc.x + W0[5]  * xc.y + W0[6]  * xc.z + W0[7]  * xc.w;
        acc += W0[8]  * xe.x + W0[9]  * xe.y + W0[10] * xe.z + W0[11] * xe.w;
        acc += W0[12] * xg.x + W0[13] * xg.y + W0[14] * xg.z + W0[15] * xg.w;
        u[((size_t)b * NR + r) * NKO + ko] = acc;   // lanes 0..63 contiguous 256B
    }
}

// ---------------------------------------------------------------------------
// per-iteration prep: blocks 0,1 -> softmax over R for k=0,1 ; block 2 -> zero s
__global__ __launch_bounds__(1024) void k_prep(const float* __restrict__ bij,
                                               float* __restrict__ c,
                                               float* __restrict__ s) {
    const int blk = blockIdx.x;
    const int t = threadIdx.x;
    if (blk == 2) {
        for (int i = t; i < NBKO; i += 1024) s[i] = 0.0f;
        return;
    }
    const int k = blk;
    __shared__ float red[1024];

    float m = -1e30f;
    for (int r = t; r < NR; r += 1024) m = fmaxf(m, bij[r * 2 + k]);
    red[t] = m; __syncthreads();
    for (int off = 512; off > 0; off >>= 1) {
        if (t < off) red[t] = fmaxf(red[t], red[t + off]);
        __syncthreads();
    }
    m = red[0];
    __syncthreads();

    float ssum = 0.0f;
    for (int r = t; r < NR; r += 1024) {
        float e = expf(bij[r * 2 + k] - m);
        c[r * 2 + k] = e;
        ssum += e;
    }
    red[t] = ssum; __syncthreads();
    for (int off = 512; off > 0; off >>= 1) {
        if (t < off) red[t] += red[t + off];
        __syncthreads();
    }
    float inv = 1.0f / red[0];
    for (int r = t; r < NR; r += 1024) c[r * 2 + k] *= inv;
}

// ---------------------------------------------------------------------------
// s[b,ko] = sum_r c[r,k] * u_hat[b,r,ko]   (grid: 72 r-chunks x 128 b)
__global__ __launch_bounds__(256) void k_sred(const float* __restrict__ u,
                                              const float* __restrict__ c,
                                              float* __restrict__ s) {
    __shared__ float cl[128];   // 64 r x 2 k
    __shared__ float red[256];
    const int chunk = blockIdx.x;     // 0..71
    const int b     = blockIdx.y;     // 0..127
    const int t     = threadIdx.x;
    const int r0    = chunk * 64;

    if (t < 128) cl[t] = c[r0 * 2 + t];
    __syncthreads();

    const int ko = t & 63;
    const int rg = t >> 6;
    const int k  = ko >> 5;
    const float* ub = u + ((size_t)b * NR + r0) * NKO + ko;

    float acc = 0.0f;
#pragma unroll
    for (int j = 0; j < 16; ++j) {
        int rr = rg + 4 * j;
        acc += cl[rr * 2 + k] * ub[(size_t)rr * NKO];
    }
    red[t] = acc; __syncthreads();
    if (t < 64) {
        float tot = red[t] + red[t + 64] + red[t + 128] + red[t + 192];
        atomicAdd(&s[b * NKO + t], tot);
    }
}

// ---------------------------------------------------------------------------
// squash: one block, thread t handles (b,k) pair t; 32 o's each.
__global__ __launch_bounds__(256) void k_squash(const float* __restrict__ s,
                                                float* __restrict__ v,
                                                float* __restrict__ out,
                                                int last) {
    const int t = threadIdx.x;   // 0..255 = b*2+k
    const float* sp = s + t * NO;
    float loc[NO];
    float sn = 0.0f;
#pragma unroll
    for (int o = 0; o < NO; ++o) { loc[o] = sp[o]; sn += loc[o] * loc[o]; }
    float f = sn / ((0.5f + sn) * sqrtf(sn));
    float* vp = v + t * NO;
#pragma unroll
    for (int o = 0; o < NO; ++o) vp[o] = loc[o] * f;
    if (last) {
        float* op = out + t * NO;
#pragma unroll
        for (int o = 0; o < NO; ++o) op[o] = loc[o] * f;
    }
}

// ---------------------------------------------------------------------------
// bij[r,k] += (1/B) * sum_b sum_o u_hat[b,r,ko] * v[b,ko]   (one block per r)
__global__ __launch_bounds__(256) void k_agree(const float* __restrict__ u,
                                               const float* __restrict__ v,
                                               float* __restrict__ bij) {
    const int r = blockIdx.x;
    const int t = threadIdx.x;
    const int ko = t & 63;
    const int w  = t >> 6;

    float acc = 0.0f;
    for (int j = 0; j < 32; ++j) {
        int b = w + 4 * j;
        acc += u[((size_t)b * NR + r) * NKO + ko] * v[b * NKO + ko];
    }
    // reduce over the 32 o-lanes within each k-half (masks < 32 stay in half)
#pragma unroll
    for (int m = 16; m > 0; m >>= 1) acc += __shfl_xor(acc, m);

    __shared__ float red[8];
    if ((ko & 31) == 0) red[w * 2 + (ko >> 5)] = acc;
    __syncthreads();
    if (t < 2) {
        float tot = red[t] + red[2 + t] + red[4 + t] + red[6 + t];
        bij[r * 2 + t] += tot * (1.0f / NB);
    }
}

// ---------------------------------------------------------------------------
extern "C" void kernel_launch(void* const* d_in, const int* in_sizes, int n_in,
                              void* d_out, int out_size, void* d_ws, size_t ws_size,
                              hipStream_t stream) {
    const float* x = (const float*)d_in[0];   // [B,R,I]
    const float* W = (const float*)d_in[1];   // [1,R,K,O,I]
    float* out = (float*)d_out;               // [B,K,O]
    float* ws  = (float*)d_ws;

    float* u   = ws + U_OFF;
    float* s   = ws + S_OFF;
    float* v   = ws + V_OFF;
    float* bij = ws + BIJ_OFF;
    float* c   = ws + C_OFF;

    k_zero_bij<<<(NRK + 255) / 256, 256, 0, stream>>>(bij);
    k_uhat<<<NR, 256, 0, stream>>>(x, W, u);

    for (int it = 0; it < 3; ++it) {
        k_prep<<<3, 1024, 0, stream>>>(bij, c, s);
        k_sred<<<dim3(72, 128), 256, 0, stream>>>(u, c, s);
        k_squash<<<1, 256, 0, stream>>>(s, v, out, it == 2 ? 1 : 0);
        if (it < 2) k_agree<<<NR, 256, 0, stream>>>(u, v, bij);
    }
}